// Round 1
// baseline (32047.305 us; speedup 1.0000x reference)
//
#include <hip/hip_runtime.h>
#include <math.h>

// Problem constants (from reference)
#define T_STEPS 8192
#define INPUT   64
#define UNITS   1024
#define NMOD    4
#define LEAKY   0.9f

// Decomposition: 32 WGs per module, each WG owns 32 columns.
// WG = 1024 threads = 16 waves; each half-wave (32 lanes) owns one column.
#define K_WG        32
#define COLS_PER_WG 32
#define NWG         (NMOD * K_WG)   // 128 workgroups, 1 per CU
#define WGSIZE      1024

// d_ws layout: hbuf[2][NMOD*UNITS] floats (32 KB), then flags[NWG] ints.
#define HBUF_FLOATS (2 * NMOD * UNITS)

__global__ void init_ws_kernel(float* __restrict__ hbuf, int* __restrict__ flags) {
    int i = threadIdx.x;
    for (int k = i; k < HBUF_FLOATS; k += WGSIZE) hbuf[k] = 0.0f;
    if (i < NWG) flags[i] = 0;
}

__global__ __launch_bounds__(WGSIZE, 1)
void reservoir_persist(const float* __restrict__ u,
                       const float* __restrict__ kern,
                       const float* __restrict__ rec,
                       const float* __restrict__ bias,
                       float* __restrict__ out,
                       float* __restrict__ hbuf,
                       int* __restrict__ flags)
{
    const int wg   = blockIdx.x;       // 0..127
    const int m    = wg / K_WG;        // module 0..3
    const int wgi  = wg % K_WG;        // index within module 0..31
    const int tid  = threadIdx.x;
    const int wave = tid >> 6;         // 0..15
    const int lane = tid & 63;
    const int half = lane >> 5;        // 0/1: which column of this wave
    const int q    = lane & 31;        // position within half-wave

    const int colBase = wgi * COLS_PER_WG;
    const int c       = colBase + wave * 2 + half;  // column within module, 0..1023

    __shared__ float h_lds[UNITS];          // current h for this module
    __shared__ float h_new[COLS_PER_WG];    // this WG's freshly computed columns

    // ---- one-time preload of weights into registers ----
    // rec[m][u][c] for u = q + 32*j  (j = 0..31): 32 VGPRs per lane
    const float* recm = rec + (size_t)m * UNITS * UNITS;
    float r[32];
#pragma unroll
    for (int j = 0; j < 32; ++j)
        r[j] = recm[(size_t)(q + 32 * j) * UNITS + c];

    const float* km = kern + (size_t)m * INPUT * UNITS;
    const float k0 = km[(size_t)q * UNITS + c];          // i = q
    const float k1 = km[(size_t)(q + 32) * UNITS + c];   // i = q+32
    const float bc = bias[m * UNITS + c];

    const float leak = LEAKY;          // 0.9
    const float omleak = 1.0f - LEAKY; // 0.1

    // h_0 = 0
    h_lds[tid] = 0.0f;
    __syncthreads();

    int* fl = flags + m * K_WG;

    // prefetch u row 0
    float u0 = u[q];
    float u1 = u[q + 32];

    for (int t = 1; t <= T_STEPS; ++t) {
        // ---- recurrent dot + input projection, per half-wave column ----
        float acc0 = 0.f, acc1 = 0.f, acc2 = 0.f, acc3 = 0.f;
#pragma unroll
        for (int j = 0; j < 32; j += 4) {
            acc0 = fmaf(r[j],     h_lds[q + 32 * j],       acc0);
            acc1 = fmaf(r[j + 1], h_lds[q + 32 * (j + 1)], acc1);
            acc2 = fmaf(r[j + 2], h_lds[q + 32 * (j + 2)], acc2);
            acc3 = fmaf(r[j + 3], h_lds[q + 32 * (j + 3)], acc3);
        }
        float acc = (acc0 + acc1) + (acc2 + acc3);
        acc = fmaf(u0, k0, acc);
        acc = fmaf(u1, k1, acc);

        // reduce across the 32 lanes of each half-wave (xor masks <32 stay in-half)
        acc += __shfl_xor(acc, 16, 64);
        acc += __shfl_xor(acc, 8, 64);
        acc += __shfl_xor(acc, 4, 64);
        acc += __shfl_xor(acc, 2, 64);
        acc += __shfl_xor(acc, 1, 64);

        // prefetch next u row (independent of h; overlaps with publish/poll)
        float nu0 = 0.f, nu1 = 0.f;
        if (t < T_STEPS) {
            nu0 = u[(size_t)t * INPUT + q];
            nu1 = u[(size_t)t * INPUT + q + 32];
        }

        if (q == 0) {  // lanes 0 and 32: leaders of the two columns
            float sv = acc + bc;
            float o = tanhf(sv);
            float hn = omleak * h_lds[c] + leak * o;
            h_new[wave * 2 + half] = hn;
        }
        __syncthreads();

        // ---- publish + sync (wave 0 only) ----
        if (wave == 0) {
            float* hw = hbuf + (size_t)(t & 1) * (NMOD * UNITS) + m * UNITS;
            if (lane < COLS_PER_WG) {
                float v = h_new[lane];
                out[(size_t)(t - 1) * (NMOD * UNITS) + m * UNITS + colBase + lane] = v;
                __hip_atomic_store(&hw[colBase + lane], v,
                                   __ATOMIC_RELAXED, __HIP_MEMORY_SCOPE_AGENT);
            }
            if (lane == 0) {
                __hip_atomic_store(&fl[wgi], t,
                                   __ATOMIC_RELEASE, __HIP_MEMORY_SCOPE_AGENT);
            }
            if (lane < K_WG) {
                while (__hip_atomic_load(&fl[lane],
                                         __ATOMIC_ACQUIRE, __HIP_MEMORY_SCOPE_AGENT) < t) {
                    // spin; agent-scope load already ~600cy round trip
                }
            }
        }
        __syncthreads();

        // ---- reload full h for this module into LDS ----
        h_lds[tid] = __hip_atomic_load(
            &hbuf[(size_t)(t & 1) * (NMOD * UNITS) + m * UNITS + tid],
            __ATOMIC_RELAXED, __HIP_MEMORY_SCOPE_AGENT);

        u0 = nu0; u1 = nu1;
        __syncthreads();
    }
}

extern "C" void kernel_launch(void* const* d_in, const int* in_sizes, int n_in,
                              void* d_out, int out_size, void* d_ws, size_t ws_size,
                              hipStream_t stream) {
    const float* u    = (const float*)d_in[0];  // [1, 8192, 64]
    const float* kern = (const float*)d_in[1];  // [4, 64, 1024]
    const float* rec  = (const float*)d_in[2];  // [4, 1024, 1024]
    const float* bias = (const float*)d_in[3];  // [4, 1024]
    float* out  = (float*)d_out;                // [1, 8192, 4096] f32
    float* hbuf = (float*)d_ws;                 // 32 KB
    int*   flags = (int*)((char*)d_ws + HBUF_FLOATS * sizeof(float));

    hipLaunchKernelGGL(init_ws_kernel, dim3(1), dim3(WGSIZE), 0, stream, hbuf, flags);

    void* args[] = { (void*)&u, (void*)&kern, (void*)&rec, (void*)&bias,
                     (void*)&out, (void*)&hbuf, (void*)&flags };
    hipLaunchCooperativeKernel((const void*)reservoir_persist,
                               dim3(NWG), dim3(WGSIZE), args, 0, stream);
}

// Round 2
// 28149.991 us; speedup vs baseline: 1.1384x; 1.1384x over previous
//
#include <hip/hip_runtime.h>
#include <math.h>

// Problem constants (from reference)
#define T_STEPS 8192
#define INPUT   64
#define UNITS   1024
#define NMOD    4
#define LEAKY   0.9f

// Decomposition: 32 WGs per module, each WG owns 32 columns.
// WG = 1024 threads = 16 waves; each half-wave (32 lanes) owns one column.
#define K_WG        32
#define COLS_PER_WG 32
#define NWG         (NMOD * K_WG)   // 128 workgroups
#define WGSIZE      1024

// d_ws layout: hb[2][NMOD*UNITS] packed {tag:32 | float:32} entries (64 KB).
#define HB_ENTRIES (2 * NMOD * UNITS)

__global__ void init_ws_kernel(unsigned long long* __restrict__ hb) {
    int i = blockIdx.x * blockDim.x + threadIdx.x;
    if (i < HB_ENTRIES) hb[i] = 0ULL;   // tag 0 < any t in 1..T
}

__global__ __launch_bounds__(WGSIZE, 1)
void reservoir_persist(const float* __restrict__ u,
                       const float* __restrict__ kern,
                       const float* __restrict__ rec,
                       const float* __restrict__ bias,
                       float* __restrict__ out,
                       unsigned long long* __restrict__ hb)
{
    const int wg   = blockIdx.x;       // 0..127
    const int m    = wg / K_WG;        // module 0..3
    const int wgi  = wg % K_WG;        // index within module 0..31
    const int tid  = threadIdx.x;
    const int wave = tid >> 6;         // 0..15
    const int lane = tid & 63;
    const int half = lane >> 5;        // 0/1: which column of this wave
    const int q    = lane & 31;        // position within half-wave

    const int colBase = wgi * COLS_PER_WG;
    const int c       = colBase + wave * 2 + half;  // column within module

    // double-buffered h in LDS -> single barrier per step
    __shared__ float h[2][UNITS];

    // ---- one-time preload of weights into registers ----
    const float* recm = rec + (size_t)m * UNITS * UNITS;
    float r[32];
#pragma unroll
    for (int j = 0; j < 32; ++j)
        r[j] = recm[(size_t)(q + 32 * j) * UNITS + c];

    const float* km = kern + (size_t)m * INPUT * UNITS;
    const float k0 = km[(size_t)q * UNITS + c];
    const float k1 = km[(size_t)(q + 32) * UNITS + c];
    const float bc = bias[m * UNITS + c];

    const float leak = LEAKY;
    const float omleak = 1.0f - LEAKY;

    h[0][tid] = 0.0f;   // h_0 = 0, consumed by step t=1 (reads h[pb^1] = h[0])
    __syncthreads();

    unsigned long long* hbm_mod = hb;  // base; indexed per step below
    const size_t modOff = (size_t)m * UNITS;

    // prefetch u row 0
    float u0 = u[q];
    float u1 = u[q + 32];

    for (int t = 1; t <= T_STEPS; ++t) {
        const int pb = t & 1;
        const float* __restrict__ hp = h[pb ^ 1];

        // ---- recurrent dot + input projection, per half-wave column ----
        float acc0 = 0.f, acc1 = 0.f, acc2 = 0.f, acc3 = 0.f;
#pragma unroll
        for (int j = 0; j < 32; j += 4) {
            acc0 = fmaf(r[j],     hp[q + 32 * j],       acc0);
            acc1 = fmaf(r[j + 1], hp[q + 32 * (j + 1)], acc1);
            acc2 = fmaf(r[j + 2], hp[q + 32 * (j + 2)], acc2);
            acc3 = fmaf(r[j + 3], hp[q + 32 * (j + 3)], acc3);
        }
        float acc = (acc0 + acc1) + (acc2 + acc3);
        acc = fmaf(u0, k0, acc);
        acc = fmaf(u1, k1, acc);

        // reduce across the 32 lanes of each half-wave
        acc += __shfl_xor(acc, 16, 64);
        acc += __shfl_xor(acc, 8, 64);
        acc += __shfl_xor(acc, 4, 64);
        acc += __shfl_xor(acc, 2, 64);
        acc += __shfl_xor(acc, 1, 64);

        // prefetch next u row (independent; overlaps publish/poll)
        float nu0 = 0.f, nu1 = 0.f;
        if (t < T_STEPS) {
            nu0 = u[(size_t)t * INPUT + q];
            nu1 = u[(size_t)t * INPUT + q + 32];
        }

        unsigned long long* hbuf_t = hbm_mod + (size_t)pb * (NMOD * UNITS) + modOff;

        if (q == 0) {  // lanes 0 and 32: leaders of the two columns
            float hn = omleak * hp[c] + leak * tanhf(acc + bc);
            unsigned long long pk =
                ((unsigned long long)(unsigned int)t << 32) | (unsigned int)__float_as_uint(hn);
            __hip_atomic_store(&hbuf_t[c], pk,
                               __ATOMIC_RELAXED, __HIP_MEMORY_SCOPE_AGENT);
        }

        // ---- single-round-trip sync: poll own element until tag == t ----
        unsigned long long w = __hip_atomic_load(&hbuf_t[tid],
                                 __ATOMIC_RELAXED, __HIP_MEMORY_SCOPE_AGENT);
        while ((unsigned int)(w >> 32) != (unsigned int)t) {
            __builtin_amdgcn_s_sleep(1);   // throttle poll traffic
            w = __hip_atomic_load(&hbuf_t[tid],
                                  __ATOMIC_RELAXED, __HIP_MEMORY_SCOPE_AGENT);
        }
        const float hv = __uint_as_float((unsigned int)w);
        h[pb][tid] = hv;

        // one designated WG per module writes the coalesced output row
        if (wgi == 0) {
            out[(size_t)(t - 1) * (NMOD * UNITS) + modOff + tid] = hv;
        }

        u0 = nu0; u1 = nu1;
        __syncthreads();   // fill of h[pb] complete; everyone done reading h[pb^1]
    }
}

extern "C" void kernel_launch(void* const* d_in, const int* in_sizes, int n_in,
                              void* d_out, int out_size, void* d_ws, size_t ws_size,
                              hipStream_t stream) {
    const float* u    = (const float*)d_in[0];  // [1, 8192, 64]
    const float* kern = (const float*)d_in[1];  // [4, 64, 1024]
    const float* rec  = (const float*)d_in[2];  // [4, 1024, 1024]
    const float* bias = (const float*)d_in[3];  // [4, 1024]
    float* out = (float*)d_out;                 // [1, 8192, 4096] f32
    unsigned long long* hb = (unsigned long long*)d_ws;  // 64 KB packed h buffer

    hipLaunchKernelGGL(init_ws_kernel, dim3((HB_ENTRIES + 1023) / 1024), dim3(1024),
                       0, stream, hb);

    void* args[] = { (void*)&u, (void*)&kern, (void*)&rec, (void*)&bias,
                     (void*)&out, (void*)&hb };
    hipLaunchCooperativeKernel((const void*)reservoir_persist,
                               dim3(NWG), dim3(WGSIZE), args, 0, stream);
}

// Round 4
// 25269.662 us; speedup vs baseline: 1.2682x; 1.1140x over previous
//
#include <hip/hip_runtime.h>
#include <math.h>

// Problem constants (from reference)
#define T_STEPS 8192
#define INPUT   64
#define UNITS   1024
#define NMOD    4
#define LEAKY   0.9f

// 32 WGs per module, 32 columns per WG, 1024 threads (16 waves) per WG.
// Each half-wave (32 lanes) owns one column; lane q owns rows 4q+128g+e.
#define K_WG        32
#define COLS_PER_WG 32
#define NWG         (NMOD * K_WG)   // 128 workgroups
#define WGSIZE      1024

// d_ws layout: hb[2][NMOD*UNITS] packed {tag:32 | float:32} entries (64 KB).
#define HB_ENTRIES (2 * NMOD * UNITS)

__global__ void init_ws_kernel(unsigned long long* __restrict__ hb) {
    int i = blockIdx.x * blockDim.x + threadIdx.x;
    if (i < HB_ENTRIES) hb[i] = 0ULL;   // tag 0 < any t in 1..T
}

// tanh via exp2 + rcp: ~1e-6 rel err, correct saturation at +/-large x.
__device__ __forceinline__ float tanh_fast(float x) {
    float e2x = __builtin_amdgcn_exp2f(x * 2.8853900817779268f); // 2*log2(e)
    float r   = __builtin_amdgcn_rcpf(e2x + 1.0f);
    return fmaf(-2.0f, r, 1.0f);
}

// Half-wave (32-lane) sum via rocPRIM-style DPP butterfly, pure VALU.
// Steps: xor1 (quad_perm), xor2 (quad_perm), xor4-equiv (row_half_mirror),
// xor8-equiv (row_mirror) -> every lane holds its 16-row sum. Then
// row_bcast:15 (row_mask 0xA) adds row0->row1 and row2->row3.
// RESULT: lanes 31 and 63 hold their half-wave sums.
__device__ __forceinline__ float halfwave_reduce_to_hi(float acc) {
    acc += __int_as_float(__builtin_amdgcn_update_dpp(
        0, __float_as_int(acc), 0xB1, 0xF, 0xF, false));   // quad_perm [1,0,3,2]
    acc += __int_as_float(__builtin_amdgcn_update_dpp(
        0, __float_as_int(acc), 0x4E, 0xF, 0xF, false));   // quad_perm [2,3,0,1]
    acc += __int_as_float(__builtin_amdgcn_update_dpp(
        0, __float_as_int(acc), 0x141, 0xF, 0xF, false));  // row_half_mirror
    acc += __int_as_float(__builtin_amdgcn_update_dpp(
        0, __float_as_int(acc), 0x140, 0xF, 0xF, false));  // row_mirror
    acc += __int_as_float(__builtin_amdgcn_update_dpp(
        0, __float_as_int(acc), 0x142, 0xA, 0xF, false));  // row_bcast:15 -> rows 1,3
    return acc;   // valid at lanes 31 and 63
}

__global__ __launch_bounds__(WGSIZE, 1)
void reservoir_persist(const float* __restrict__ u,
                       const float* __restrict__ kern,
                       const float* __restrict__ rec,
                       const float* __restrict__ bias,
                       float* __restrict__ out,
                       unsigned long long* __restrict__ hb)
{
    const int wg   = blockIdx.x;       // 0..127
    const int m    = wg / K_WG;        // module 0..3
    const int wgi  = wg % K_WG;        // index within module 0..31
    const int tid  = threadIdx.x;
    const int wave = tid >> 6;         // 0..15
    const int lane = tid & 63;
    const int half = lane >> 5;        // 0/1: which column of this wave
    const int q    = lane & 31;        // position within half-wave

    const int colBase = wgi * COLS_PER_WG;
    const int c       = colBase + wave * 2 + half;  // column within module

    // double-buffered h in LDS -> single barrier per step
    __shared__ __align__(16) float h[2][UNITS];

    // ---- one-time preload of weights into registers ----
    // lane q owns rows 4q + 128g + e (g=0..7, e=0..3): float4-contiguous groups
    const float* recm = rec + (size_t)m * UNITS * UNITS;
    float r[32];
#pragma unroll
    for (int g = 0; g < 8; ++g)
#pragma unroll
        for (int e = 0; e < 4; ++e)
            r[4 * g + e] = recm[(size_t)(4 * q + 128 * g + e) * UNITS + c];

    const float* km = kern + (size_t)m * INPUT * UNITS;
    const float k0 = km[(size_t)q * UNITS + c];
    const float k1 = km[(size_t)(q + 32) * UNITS + c];
    const float bc = bias[m * UNITS + c];

    const float leak = LEAKY;
    const float omleak = 1.0f - LEAKY;

    h[0][tid] = 0.0f;   // h_0 = 0, consumed by step t=1
    __syncthreads();

    const size_t modOff = (size_t)m * UNITS;

    // prefetch u row 0
    float u0 = u[q];
    float u1 = u[q + 32];

    for (int t = 1; t <= T_STEPS; ++t) {
        const int pb = t & 1;
        const float* __restrict__ hp = h[pb ^ 1];
        const float4* __restrict__ hp4 = reinterpret_cast<const float4*>(hp);

        // ---- recurrent dot: 8x ds_read_b128 + 32 FMA per lane ----
        float acc0 = 0.f, acc1 = 0.f, acc2 = 0.f, acc3 = 0.f;
#pragma unroll
        for (int g = 0; g < 8; ++g) {
            float4 hv = hp4[q + 32 * g];
            acc0 = fmaf(r[4 * g + 0], hv.x, acc0);
            acc1 = fmaf(r[4 * g + 1], hv.y, acc1);
            acc2 = fmaf(r[4 * g + 2], hv.z, acc2);
            acc3 = fmaf(r[4 * g + 3], hv.w, acc3);
        }
        float acc = (acc0 + acc1) + (acc2 + acc3);
        acc = fmaf(u0, k0, acc);
        acc = fmaf(u1, k1, acc);

        // ---- pure-VALU reduction; result at lanes 31 and 63 ----
        acc = halfwave_reduce_to_hi(acc);

        // prefetch next u row (independent; overlaps publish/poll)
        float nu0 = 0.f, nu1 = 0.f;
        if (t < T_STEPS) {
            nu0 = u[(size_t)t * INPUT + q];
            nu1 = u[(size_t)t * INPUT + q + 32];
        }

        unsigned long long* hbuf_t = hb + (size_t)pb * (NMOD * UNITS) + modOff;

        if (q == 31) {  // lanes 31 and 63: leaders of the two columns
            float hn = omleak * hp[c] + leak * tanh_fast(acc + bc);
            unsigned long long pk =
                ((unsigned long long)(unsigned int)t << 32) |
                (unsigned int)__float_as_uint(hn);
            __hip_atomic_store(&hbuf_t[c], pk,
                               __ATOMIC_RELAXED, __HIP_MEMORY_SCOPE_AGENT);
        }

        // ---- single-round-trip sync: poll own element until tag == t ----
        unsigned long long w = __hip_atomic_load(&hbuf_t[tid],
                                 __ATOMIC_RELAXED, __HIP_MEMORY_SCOPE_AGENT);
        while ((unsigned int)(w >> 32) != (unsigned int)t) {
            __builtin_amdgcn_s_sleep(1);
            w = __hip_atomic_load(&hbuf_t[tid],
                                  __ATOMIC_RELAXED, __HIP_MEMORY_SCOPE_AGENT);
        }
        const float hv = __uint_as_float((unsigned int)w);
        h[pb][tid] = hv;

        // one designated WG per module writes the coalesced output row
        if (wgi == 0) {
            out[(size_t)(t - 1) * (NMOD * UNITS) + modOff + tid] = hv;
        }

        u0 = nu0; u1 = nu1;
        __syncthreads();   // h[pb] filled; everyone done reading h[pb^1]
    }
}

extern "C" void kernel_launch(void* const* d_in, const int* in_sizes, int n_in,
                              void* d_out, int out_size, void* d_ws, size_t ws_size,
                              hipStream_t stream) {
    const float* u    = (const float*)d_in[0];  // [1, 8192, 64]
    const float* kern = (const float*)d_in[1];  // [4, 64, 1024]
    const float* rec  = (const float*)d_in[2];  // [4, 1024, 1024]
    const float* bias = (const float*)d_in[3];  // [4, 1024]
    float* out = (float*)d_out;                 // [1, 8192, 4096] f32
    unsigned long long* hb = (unsigned long long*)d_ws;  // 64 KB packed h buffer

    hipLaunchKernelGGL(init_ws_kernel, dim3((HB_ENTRIES + 1023) / 1024), dim3(1024),
                       0, stream, hb);

    void* args[] = { (void*)&u, (void*)&kern, (void*)&rec, (void*)&bias,
                     (void*)&out, (void*)&hb };
    hipLaunchCooperativeKernel((const void*)reservoir_persist,
                               dim3(NWG), dim3(WGSIZE), args, 0, stream);
}